// Round 10
// baseline (281.351 us; speedup 1.0000x reference)
//
#include <hip/hip_runtime.h>
#include <stdint.h>

// KNN K=16 over x (B=2, N=8192, D=64) f32. Output int32 (2,B,N,K): nn_idx, center_idx.
// Pipeline: split_k (bf16 hi/lo + norms) -> tau_p (MFMA partial top-2 ladders over
// 2048-sample, 32q/block) -> tau_m (merge -> per-query provable threshold) ->
// filter_k (MFMA bf16 3-term split distance, reg-prefetched B staging, LDS accepts,
// no global atomics) -> rerank_k (exact f64, wave-per-query + 64-lane bitonic).
// Threshold correctness: 16th-smallest of ANY subset of sample keys >= sample-16th
// >= true d16 (pigeonhole); slop covers bf16-split approx error, so all true
// top-16 provably survive the filter.
constexpr int N_   = 8192;
constexpr int D_   = 64;
constexpr int K_   = 16;
constexpr int NQ   = 16384;           // 2*8192
constexpr int MS   = 8;               // m-superblocks per batch (1024 m each)
constexpr int CAPB = 32;              // survivor cap per (query, m-superblock): E=8, +8.5 sigma
constexpr float SLOP = 0.012f;        // per-stage slop >> 2*eps(bf16-split ~1.3e-3)

typedef __attribute__((ext_vector_type(8))) short bf16x8;
typedef __attribute__((ext_vector_type(4))) float f32x4;

template<int JN>
__device__ __forceinline__ void topk_insertf(float (&key)[JN], float nk) {
    if (nk < key[JN - 1]) {
        bool c[JN];
#pragma unroll
        for (int j = 0; j < JN; ++j) c[j] = nk < key[j];
#pragma unroll
        for (int j = JN - 1; j >= 1; --j)
            key[j] = c[j - 1] ? key[j - 1] : (c[j] ? nk : key[j]);
        key[0] = c[0] ? nk : key[0];
    }
}

__device__ __forceinline__ unsigned short bf16_rne(float f) {
    uint32_t u = __float_as_uint(f);
    return (unsigned short)((u + 0x7FFFu + ((u >> 16) & 1u)) >> 16);   // no NaN in data
}

#define SWZ(r, s) (((r) << 7) + ((((s) ^ ((r) & 7))) << 4))

// K1: bf16 hi/lo split + squared norms. 16 lanes per row (coalesced). grid = 1024.
__global__ void __launch_bounds__(256) split_k(const float* __restrict__ x,
                                               unsigned short* __restrict__ xh,
                                               unsigned short* __restrict__ xl,
                                               float* __restrict__ nrm) {
    const int t = blockIdx.x * 256 + (int)threadIdx.x;    // one float4 per thread
    const int row = t >> 4, seg = t & 15;
    const float4 v = reinterpret_cast<const float4*>(x)[t];
    float f[4] = {v.x, v.y, v.z, v.w};
    unsigned short h[4], l[4];
    float sq = 0.f;
#pragma unroll
    for (int j = 0; j < 4; ++j) {
        sq = fmaf(f[j], f[j], sq);
        h[j] = bf16_rne(f[j]);
        float hf = __uint_as_float((uint32_t)h[j] << 16);
        l[j] = bf16_rne(f[j] - hf);                       // residual exact in f32
    }
    sq += __shfl_xor(sq, 1, 16); sq += __shfl_xor(sq, 2, 16);
    sq += __shfl_xor(sq, 4, 16); sq += __shfl_xor(sq, 8, 16);
    if (seg == 0) nrm[row] = sq;
    ushort4 hv = {h[0], h[1], h[2], h[3]}, lv = {l[0], l[1], l[2], l[3]};
    reinterpret_cast<ushort4*>(xh)[t] = hv;
    reinterpret_cast<ushort4*>(xl)[t] = lv;
}

// K2a: MFMA tau partials. Block = 32 q x 2048 samples (16 chunks of 128).
// Per (lane, q-row) a branchless depth-2 ladder (min + clamp) over the 32 sample
// keys that lane sees -> 128 partials/query. grid = NQ/32 = 512 (2 blocks/CU).
__global__ void __launch_bounds__(256) tau_p(const unsigned short* __restrict__ xh,
                                             const unsigned short* __restrict__ xl,
                                             const float* __restrict__ nrm,
                                             float* __restrict__ part) {
    __shared__ alignas(16) unsigned short A[64 * 64];     // 8 KB: rows 0-31 q-hi, 32-63 q-lo
    __shared__ alignas(16) unsigned short Bb[256 * 64];   // 32 KB: rows 0-127 s-hi, 128-255 s-lo
    __shared__ float nrmb[128];
    const int tid = (int)threadIdx.x;
    const int q0g = (int)blockIdx.x * 32;                 // global query base
    const int b   = q0g >> 13;                            // uniform (32 | 8192)
    const int n0  = q0g & (N_ - 1);
    const unsigned short* __restrict__ xhb = xh + (size_t)b * N_ * D_;
    const unsigned short* __restrict__ xlb = xl + (size_t)b * N_ * D_;
    const float* __restrict__ nb = nrm + b * N_;

#pragma unroll
    for (int k = 0; k < 2; ++k) {                         // stage A: 64 rows x 8 segs
        int u = tid + k * 256, r = u >> 3, s = u & 7;
        const unsigned short* src = (r < 32) ? xhb + (size_t)(n0 + r) * D_
                                             : xlb + (size_t)(n0 + r - 32) * D_;
        *(float4*)((char*)A + SWZ(r, s)) = *(const float4*)((const char*)src + (s << 4));
    }

    const int wave = tid >> 6, lane = tid & 63;
    const int l15 = lane & 15, quad = lane >> 4;

    float lad0[8], lad1[8];
#pragma unroll
    for (int j = 0; j < 8; ++j) { lad0[j] = __builtin_inff(); lad1[j] = __builtin_inff(); }

    for (int mc = 0; mc < 16; ++mc) {
        const int m0 = mc * 128;
        __syncthreads();                                  // A/prev-compute done
#pragma unroll
        for (int k = 0; k < 8; ++k) {                     // stage B chunk (hi+lo)
            int u = tid + k * 256, r = u >> 3, s = u & 7;
            const unsigned short* src = (r < 128) ? xhb + (size_t)(m0 + r) * D_
                                                  : xlb + (size_t)(m0 + r - 128) * D_;
            *(float4*)((char*)Bb + SWZ(r, s)) = *(const float4*)((const char*)src + (s << 4));
        }
        if (tid < 128) nrmb[tid] = nb[m0 + tid];
        __syncthreads();

        f32x4 acc[2][2] = {};
#pragma unroll
        for (int half = 0; half < 2; ++half) {
            const int seg = half * 4 + quad;
            bf16x8 afh[2], afl[2], bfh[2], bfl[2];
#pragma unroll
            for (int tm = 0; tm < 2; ++tm) {
                afh[tm] = *(const bf16x8*)((const char*)A + SWZ(tm * 16 + l15, seg));
                afl[tm] = *(const bf16x8*)((const char*)A + SWZ(32 + tm * 16 + l15, seg));
            }
#pragma unroll
            for (int tn = 0; tn < 2; ++tn) {
                bfh[tn] = *(const bf16x8*)((const char*)Bb + SWZ(wave * 32 + tn * 16 + l15, seg));
                bfl[tn] = *(const bf16x8*)((const char*)Bb + SWZ(128 + wave * 32 + tn * 16 + l15, seg));
            }
#pragma unroll
            for (int tm = 0; tm < 2; ++tm)
#pragma unroll
                for (int tn = 0; tn < 2; ++tn) {
                    acc[tm][tn] = __builtin_amdgcn_mfma_f32_16x16x32_bf16(afh[tm], bfh[tn], acc[tm][tn], 0, 0, 0);
                    acc[tm][tn] = __builtin_amdgcn_mfma_f32_16x16x32_bf16(afh[tm], bfl[tn], acc[tm][tn], 0, 0, 0);
                    acc[tm][tn] = __builtin_amdgcn_mfma_f32_16x16x32_bf16(afl[tm], bfh[tn], acc[tm][tn], 0, 0, 0);
                }
        }
        // epilogue: C/D col=lane&15 (sample), row=quad*4+reg (query); depth-2 ladder
#pragma unroll
        for (int tn = 0; tn < 2; ++tn) {
            const float nm = nrmb[wave * 32 + tn * 16 + l15];
#pragma unroll
            for (int tm = 0; tm < 2; ++tm)
#pragma unroll
                for (int reg = 0; reg < 4; ++reg) {
                    float keyf = fmaf(-2.f, acc[tm][tn][reg], nm);
                    const int li = tm * 4 + reg;
                    float k0 = lad0[li];
                    lad0[li] = fminf(k0, keyf);
                    lad1[li] = fminf(fmaxf(keyf, k0), lad1[li]);   // clamp = med3
                }
        }
    }
    // dump partials: part[q][wave*16+l15] as float2 (128 floats / query)
#pragma unroll
    for (int tm = 0; tm < 2; ++tm)
#pragma unroll
        for (int reg = 0; reg < 4; ++reg) {
            const int r = tm * 16 + quad * 4 + reg;
            const int li = tm * 4 + reg;
            float2 v = {lad0[li], lad1[li]};
            *(float2*)(part + ((size_t)(q0g + r)) * 128 + (wave * 16 + l15) * 2) = v;
        }
}

// K2b: merge 128 partials/query -> tau. Thread per query; block 64 so all 256
// CUs participate. grid = NQ/64 = 256.
__global__ void __launch_bounds__(64) tau_m(const float* __restrict__ part,
                                            float* __restrict__ tau) {
    const int q = blockIdx.x * 64 + (int)threadIdx.x;
    const float4* p = reinterpret_cast<const float4*>(part + (size_t)q * 128);
    float key[K_];
#pragma unroll
    for (int j = 0; j < K_; ++j) key[j] = __builtin_inff();
    for (int i = 0; i < 32; ++i) {
        float4 v = p[i];
        topk_insertf<K_>(key, v.x); topk_insertf<K_>(key, v.y);
        topk_insertf<K_>(key, v.z); topk_insertf<K_>(key, v.w);
    }
    tau[q] = key[15] + SLOP;
}

// K3: MFMA filter, B-reuse. Block = 128q x 1024m (8 chunks of 128m). A (hi+lo,
// 32 KB) staged once; B per chunk (32 KB) REGISTER-PREFETCHED one chunk ahead so
// the vmcnt drain lands after the MFMA block. Per half: load afh/afl/bfh/bfl once
// (32 ds_read_b128/chunk, was 48) and issue all 3 split-term MFMAs from regs.
// nrm tile staged in LDS once. Accepts -> LDS per-query lists (DS atomics only),
// flushed to fixed per-(q,ms) global slots. grid = 2*64*8 = 1024 blocks of 256.
__global__ void __launch_bounds__(256, 2) filter_k(const unsigned short* __restrict__ xh,
                                                   const unsigned short* __restrict__ xl,
                                                   const float* __restrict__ nrm,
                                                   const float* __restrict__ tau,
                                                   unsigned short* __restrict__ cnt_pb,
                                                   unsigned short* __restrict__ buf2) {
    __shared__ alignas(16) unsigned short A[256 * 64];    // 32 KB: rows 0-127 hi, 128-255 lo
    __shared__ alignas(16) unsigned short Bb[256 * 64];   // 32 KB
    __shared__ alignas(16) float taub[128];
    __shared__ alignas(16) float nrmS[1024];              // 4 KB superblock norms
    __shared__ unsigned short lists[128 * CAPB];          // 8 KB
    __shared__ unsigned int cntL[128];
    const int tid = (int)threadIdx.x;
    const int bid = (int)blockIdx.x;
    const int b  = bid >> 9;
    const int qt = (bid >> 3) & 63;
    const int ms = bid & 7;
    const int q0 = qt * 128;
    const unsigned short* __restrict__ xhb = xh + (size_t)b * N_ * D_;
    const unsigned short* __restrict__ xlb = xl + (size_t)b * N_ * D_;
    const float* __restrict__ nb = nrm + b * N_;

#pragma unroll
    for (int k = 0; k < 8; ++k) {                         // stage A (hi+lo)
        int u = tid + k * 256, r = u >> 3, s = u & 7;
        const unsigned short* src = (r < 128) ? xhb + (size_t)(q0 + r) * D_
                                              : xlb + (size_t)(q0 + r - 128) * D_;
        *(float4*)((char*)A + SWZ(r, s)) = *(const float4*)((const char*)src + (s << 4));
    }
    {                                                     // stage B chunk 0
        const int m0 = ms * 1024;
#pragma unroll
        for (int k = 0; k < 8; ++k) {
            int u = tid + k * 256, r = u >> 3, s = u & 7;
            const unsigned short* src = (r < 128) ? xhb + (size_t)(m0 + r) * D_
                                                  : xlb + (size_t)(m0 + r - 128) * D_;
            *(float4*)((char*)Bb + SWZ(r, s)) = *(const float4*)((const char*)src + (s << 4));
        }
    }
    *(float4*)(nrmS + tid * 4) = *(const float4*)(nb + ms * 1024 + tid * 4);
    if (tid < 128) { cntL[tid] = 0; taub[tid] = tau[(b << 13) + q0 + tid]; }
    __syncthreads();

    const int wave = tid >> 6, lane = tid & 63;
    const int wq = wave >> 1, wm = wave & 1;              // 64x64 wave subtile
    const int l15 = lane & 15, quad = lane >> 4;

    for (int mc = 0; mc < 8; ++mc) {
        float4 pre[8];
        if (mc < 7) {                                     // prefetch next B chunk to regs
            const int m0n = ms * 1024 + (mc + 1) * 128;
#pragma unroll
            for (int k = 0; k < 8; ++k) {
                int u = tid + k * 256, r = u >> 3, s = u & 7;
                const unsigned short* src = (r < 128) ? xhb + (size_t)(m0n + r) * D_
                                                      : xlb + (size_t)(m0n + r - 128) * D_;
                pre[k] = *(const float4*)((const char*)src + (s << 4));
            }
        }

        f32x4 acc[4][4] = {};
#pragma unroll
        for (int half = 0; half < 2; ++half) {
            const int seg = half * 4 + quad;
            bf16x8 afh[4], afl[4], bfh[4], bfl[4];
#pragma unroll
            for (int tm = 0; tm < 4; ++tm) {
                afh[tm] = *(const bf16x8*)((const char*)A + SWZ(wq * 64 + tm * 16 + l15, seg));
                afl[tm] = *(const bf16x8*)((const char*)A + SWZ(128 + wq * 64 + tm * 16 + l15, seg));
            }
#pragma unroll
            for (int tn = 0; tn < 4; ++tn) {
                bfh[tn] = *(const bf16x8*)((const char*)Bb + SWZ(wm * 64 + tn * 16 + l15, seg));
                bfl[tn] = *(const bf16x8*)((const char*)Bb + SWZ(128 + wm * 64 + tn * 16 + l15, seg));
            }
#pragma unroll
            for (int tm = 0; tm < 4; ++tm)
#pragma unroll
                for (int tn = 0; tn < 4; ++tn) {
                    acc[tm][tn] = __builtin_amdgcn_mfma_f32_16x16x32_bf16(afh[tm], bfh[tn], acc[tm][tn], 0, 0, 0);
                    acc[tm][tn] = __builtin_amdgcn_mfma_f32_16x16x32_bf16(afh[tm], bfl[tn], acc[tm][tn], 0, 0, 0);
                    acc[tm][tn] = __builtin_amdgcn_mfma_f32_16x16x32_bf16(afl[tm], bfh[tn], acc[tm][tn], 0, 0, 0);
                }
        }

        // epilogue: C/D layout col=lane&15 (m), row=quad*4+reg (q)
        float nmv[4]; int mlv[4];
#pragma unroll
        for (int tn = 0; tn < 4; ++tn) {
            mlv[tn] = mc * 128 + wm * 64 + tn * 16 + l15;  // local m within superblock
            nmv[tn] = nrmS[mlv[tn]];
        }
        f32x4 t4v[4];
#pragma unroll
        for (int tm = 0; tm < 4; ++tm) {
            f32x4 t4 = *(const f32x4*)(taub + wq * 64 + tm * 16 + quad * 4);
            t4v[tm] = t4 + SLOP;
        }
#pragma unroll
        for (int tm = 0; tm < 4; ++tm)
#pragma unroll
            for (int tn = 0; tn < 4; ++tn)
#pragma unroll
                for (int reg = 0; reg < 4; ++reg) {
                    float keyf = fmaf(-2.f, acc[tm][tn][reg], nmv[tn]);
                    if (keyf <= t4v[tm][reg]) {
                        int ql = wq * 64 + tm * 16 + quad * 4 + reg;     // local q
                        unsigned pos = atomicAdd(&cntL[ql], 1u);         // LDS atomic
                        if (pos < CAPB) lists[ql * CAPB + pos] = (unsigned short)(ms * 1024 + mlv[tn]);
                    }
                }

        __syncthreads();                                   // all waves done reading Bb
        if (mc < 7) {
#pragma unroll
            for (int k = 0; k < 8; ++k) {                  // commit prefetched chunk
                int u = tid + k * 256, r = u >> 3, s = u & 7;
                *(float4*)((char*)Bb + SWZ(r, s)) = pre[k];
            }
        }
        __syncthreads();                                   // Bb(mc+1) visible
    }
    if (tid < 128) {                                       // flush to fixed slots
        int q = (b << 13) + q0 + tid;
        unsigned cn = cntL[tid]; cn = cn < CAPB ? cn : CAPB;
        cnt_pb[(size_t)q * MS + ms] = (unsigned short)cn;
        unsigned short* dst = buf2 + ((size_t)q * MS + ms) * CAPB;
        for (unsigned i = 0; i < cn; ++i) dst[i] = lists[tid * CAPB + i];
    }
}

// K4: exact f64 rerank, wave-per-query. Each lane computes one candidate's full
// 64-dim f64 distance (gather loads + LDS-broadcast Q); selection via 64-lane
// bitonic sort of packed u64 (dist,id) keys: keep top-16 in lanes 0-15, refill
// 48, resort. block 256 = 4 waves = 4 queries; grid = NQ/4 = 4096.
__global__ void __launch_bounds__(256) rerank_k(const float* __restrict__ x,
                                                const unsigned short* __restrict__ cnt_pb,
                                                const unsigned short* __restrict__ buf2,
                                                int* __restrict__ out) {
    __shared__ float Qs[4 * 64];                           // 1 KB query rows
    __shared__ unsigned short ids[4 * MS * CAPB];          // 2 KB compacted survivors
    const int tid = (int)threadIdx.x;
    const int w = tid >> 6, lane = tid & 63;
    const int q = blockIdx.x * 4 + w;
    const int b = q >> 13, n = q & (N_ - 1);
    const float* __restrict__ xb = x + (size_t)b * N_ * D_;
    Qs[w * 64 + lane] = xb[(size_t)n * D_ + lane];

    int off[MS + 1]; off[0] = 0;                           // all lanes compute same
#pragma unroll
    for (int ms = 0; ms < MS; ++ms) {
        int c = (int)cnt_pb[(size_t)q * MS + ms]; c = c < CAPB ? c : CAPB;
        off[ms + 1] = off[ms] + c;
    }
    const int total = off[MS];                             // >= 16 guaranteed (true top-16 pass)
    for (int idx = lane; idx < total; idx += 64) {         // compact ids into LDS
        int ms = 0;
#pragma unroll
        for (int t = 1; t < MS; ++t) ms += (idx >= off[t]) ? 1 : 0;
        ids[(w * MS) * CAPB + idx] = buf2[((size_t)q * MS + ms) * CAPB + (idx - off[ms])];
    }
    __syncthreads();

    unsigned long long v = ~0ull;
    int consumed = 0;
    bool first = true;
    while (first || consumed < total) {
        const int myIdx = first ? lane : consumed + lane - 16;
        const bool take = (first || lane >= 16) && myIdx < total;
        unsigned long long nk = ~0ull;
        if (take) {
            const int id = (int)ids[(w * MS) * CAPB + myIdx];
            const float* __restrict__ crow = xb + (size_t)id * D_;
            double a0 = 0.0, a1 = 0.0, a2 = 0.0, a3 = 0.0;
#pragma unroll
            for (int j = 0; j < 16; ++j) {
                const float4 c  = *(const float4*)(crow + j * 4);        // per-lane gather
                const float4 qv = *(const float4*)(Qs + w * 64 + j * 4); // uniform -> broadcast
                double d0 = (double)qv.x - (double)c.x; a0 = fma(d0, d0, a0);
                double d1 = (double)qv.y - (double)c.y; a1 = fma(d1, d1, a1);
                double d2 = (double)qv.z - (double)c.z; a2 = fma(d2, d2, a2);
                double d3 = (double)qv.w - (double)c.w; a3 = fma(d3, d3, a3);
            }
            double s = (a0 + a1) + (a2 + a3);
            // s >= 0 -> f64 bits order-preserving; low 13 mantissa bits carry the id
            // for exact (dist, id) lexicographic compare (ties -> lower id).
            nk = ((unsigned long long)__double_as_longlong(s) & ~0x1FFFull) | (unsigned)id;
        }
        if (first || lane >= 16) v = nk;                   // lanes 0-15 keep running top-16
        // 64-lane bitonic sort ascending (21 steps)
#pragma unroll
        for (int k = 2; k <= 64; k <<= 1)
#pragma unroll
            for (int j = k >> 1; j > 0; j >>= 1) {
                unsigned long long o = __shfl_xor(v, j, 64);
                const bool keepmin = (((lane & k) == 0) == ((lane & j) == 0));
                unsigned long long mn = v < o ? v : o;
                unsigned long long mx = v < o ? o : v;
                v = keepmin ? mn : mx;
            }
        consumed += first ? 64 : 48;
        first = false;
    }
    if (lane < K_) {
        out[(size_t)q * K_ + lane]                   = (int)(v & 0x1FFFull);  // nn_idx
        out[(size_t)NQ * K_ + (size_t)q * K_ + lane] = n;                     // center_idx
    }
}

extern "C" void kernel_launch(void* const* d_in, const int* in_sizes, int n_in,
                              void* d_out, int out_size, void* d_ws, size_t ws_size,
                              hipStream_t stream) {
    const float* x = (const float*)d_in[0];
    int* out = (int*)d_out;
    char* ws = (char*)d_ws;
    float*          nrm    = (float*)ws;                          //  64 KB @ 0
    float*          tau    = (float*)(ws + (64 << 10));           //  64 KB
    unsigned short* cnt_pb = (unsigned short*)(ws + (128 << 10)); // 256 KB (16384*8*2)
    unsigned short* xh     = (unsigned short*)(ws + (1 << 20));   //   2 MB
    unsigned short* xl     = (unsigned short*)(ws + (3 << 20));   //   2 MB
    unsigned short* buf2   = (unsigned short*)(ws + (5 << 20));   // 8.4 MB (16384*8*32*2)
    float*          part   = (float*)(ws + (5 << 20));            //   8 MB, ALIASES buf2:
    // part is written by tau_p and fully consumed by tau_m BEFORE filter_k writes buf2.

    hipLaunchKernelGGL(split_k,  dim3(1024), dim3(256), 0, stream, x, xh, xl, nrm);
    hipLaunchKernelGGL(tau_p,    dim3(512),  dim3(256), 0, stream, xh, xl, nrm, part);
    hipLaunchKernelGGL(tau_m,    dim3(256),  dim3(64),  0, stream, part, tau);
    hipLaunchKernelGGL(filter_k, dim3(1024), dim3(256), 0, stream, xh, xl, nrm, tau, cnt_pb, buf2);
    hipLaunchKernelGGL(rerank_k, dim3(4096), dim3(256), 0, stream, x, cnt_pb, buf2, out);
}

// Round 11
// 242.211 us; speedup vs baseline: 1.1616x; 1.1616x over previous
//
#include <hip/hip_runtime.h>
#include <stdint.h>

// KNN K=16 over x (B=2, N=8192, D=64) f32. Output int32 (2,B,N,K): nn_idx, center_idx.
// Pipeline: split_k (bf16 hi/lo + norms) -> tau_p (MFMA partial top-2 ladders over
// 2048-sample, 32q/block) -> tau_m (merge -> per-query provable threshold) ->
// filter_k (MFMA bf16 3-term split distance, ASYNC global_load_lds staging, LDS
// accepts, no global atomics) -> rerank_k (exact f64, wave-per-query + bitonic).
// Threshold correctness: 16th-smallest of ANY subset of sample keys >= sample-16th
// >= true d16 (pigeonhole); slop covers bf16-split approx error, so all true
// top-16 provably survive the filter.
constexpr int N_   = 8192;
constexpr int D_   = 64;
constexpr int K_   = 16;
constexpr int NQ   = 16384;           // 2*8192
constexpr int MS   = 8;               // m-superblocks per batch (1024 m each)
constexpr int CAPB = 32;              // survivor cap per (query, m-superblock): E=8, +8.5 sigma
constexpr float SLOP = 0.012f;        // per-stage slop >> 2*eps(bf16-split ~1.3e-3)

typedef __attribute__((ext_vector_type(8))) short bf16x8;
typedef __attribute__((ext_vector_type(4))) float f32x4;

template<int JN>
__device__ __forceinline__ void topk_insertf(float (&key)[JN], float nk) {
    if (nk < key[JN - 1]) {
        bool c[JN];
#pragma unroll
        for (int j = 0; j < JN; ++j) c[j] = nk < key[j];
#pragma unroll
        for (int j = JN - 1; j >= 1; --j)
            key[j] = c[j - 1] ? key[j - 1] : (c[j] ? nk : key[j]);
        key[0] = c[0] ? nk : key[0];
    }
}

__device__ __forceinline__ unsigned short bf16_rne(float f) {
    uint32_t u = __float_as_uint(f);
    return (unsigned short)((u + 0x7FFFu + ((u >> 16) & 1u)) >> 16);   // no NaN in data
}

// async 16B global -> LDS (no VGPR round-trip; R10's reg-prefetch spilled to
// scratch: WRITE_SIZE 6->114 MB). Dest = wave-uniform LDS base + lane*16.
__device__ __forceinline__ void gl_lds16(const void* g, void* l) {
    __builtin_amdgcn_global_load_lds(
        (const __attribute__((address_space(1))) unsigned int*)g,
        (__attribute__((address_space(3))) unsigned int*)l, 16, 0, 0);
}

#define SWZ(r, s) (((r) << 7) + ((((s) ^ ((r) & 7))) << 4))

// K1: bf16 hi/lo split + squared norms. 16 lanes per row (coalesced). grid = 1024.
__global__ void __launch_bounds__(256) split_k(const float* __restrict__ x,
                                               unsigned short* __restrict__ xh,
                                               unsigned short* __restrict__ xl,
                                               float* __restrict__ nrm) {
    const int t = blockIdx.x * 256 + (int)threadIdx.x;    // one float4 per thread
    const int row = t >> 4, seg = t & 15;
    const float4 v = reinterpret_cast<const float4*>(x)[t];
    float f[4] = {v.x, v.y, v.z, v.w};
    unsigned short h[4], l[4];
    float sq = 0.f;
#pragma unroll
    for (int j = 0; j < 4; ++j) {
        sq = fmaf(f[j], f[j], sq);
        h[j] = bf16_rne(f[j]);
        float hf = __uint_as_float((uint32_t)h[j] << 16);
        l[j] = bf16_rne(f[j] - hf);                       // residual exact in f32
    }
    sq += __shfl_xor(sq, 1, 16); sq += __shfl_xor(sq, 2, 16);
    sq += __shfl_xor(sq, 4, 16); sq += __shfl_xor(sq, 8, 16);
    if (seg == 0) nrm[row] = sq;
    ushort4 hv = {h[0], h[1], h[2], h[3]}, lv = {l[0], l[1], l[2], l[3]};
    reinterpret_cast<ushort4*>(xh)[t] = hv;
    reinterpret_cast<ushort4*>(xl)[t] = lv;
}

// K2a: MFMA tau partials. Block = 32 q x 2048 samples (16 chunks of 128).
// Per (lane, q-row) a branchless depth-2 ladder (min + clamp) over the 32 sample
// keys that lane sees -> 128 partials/query. grid = NQ/32 = 512 (2 blocks/CU).
__global__ void __launch_bounds__(256) tau_p(const unsigned short* __restrict__ xh,
                                             const unsigned short* __restrict__ xl,
                                             const float* __restrict__ nrm,
                                             float* __restrict__ part) {
    __shared__ alignas(16) unsigned short A[64 * 64];     // 8 KB: rows 0-31 q-hi, 32-63 q-lo
    __shared__ alignas(16) unsigned short Bb[256 * 64];   // 32 KB: rows 0-127 s-hi, 128-255 s-lo
    __shared__ float nrmb[128];
    const int tid = (int)threadIdx.x;
    const int q0g = (int)blockIdx.x * 32;                 // global query base
    const int b   = q0g >> 13;                            // uniform (32 | 8192)
    const int n0  = q0g & (N_ - 1);
    const unsigned short* __restrict__ xhb = xh + (size_t)b * N_ * D_;
    const unsigned short* __restrict__ xlb = xl + (size_t)b * N_ * D_;
    const float* __restrict__ nb = nrm + b * N_;

#pragma unroll
    for (int k = 0; k < 2; ++k) {                         // stage A: 64 rows x 8 segs
        int u = tid + k * 256, r = u >> 3, s = u & 7;
        const unsigned short* src = (r < 32) ? xhb + (size_t)(n0 + r) * D_
                                             : xlb + (size_t)(n0 + r - 32) * D_;
        *(float4*)((char*)A + SWZ(r, s)) = *(const float4*)((const char*)src + (s << 4));
    }

    const int wave = tid >> 6, lane = tid & 63;
    const int l15 = lane & 15, quad = lane >> 4;

    float lad0[8], lad1[8];
#pragma unroll
    for (int j = 0; j < 8; ++j) { lad0[j] = __builtin_inff(); lad1[j] = __builtin_inff(); }

    for (int mc = 0; mc < 16; ++mc) {
        const int m0 = mc * 128;
        __syncthreads();                                  // A/prev-compute done
#pragma unroll
        for (int k = 0; k < 8; ++k) {                     // stage B chunk (hi+lo)
            int u = tid + k * 256, r = u >> 3, s = u & 7;
            const unsigned short* src = (r < 128) ? xhb + (size_t)(m0 + r) * D_
                                                  : xlb + (size_t)(m0 + r - 128) * D_;
            *(float4*)((char*)Bb + SWZ(r, s)) = *(const float4*)((const char*)src + (s << 4));
        }
        if (tid < 128) nrmb[tid] = nb[m0 + tid];
        __syncthreads();

        f32x4 acc[2][2] = {};
#pragma unroll
        for (int half = 0; half < 2; ++half) {
            const int seg = half * 4 + quad;
            bf16x8 afh[2], afl[2], bfh[2], bfl[2];
#pragma unroll
            for (int tm = 0; tm < 2; ++tm) {
                afh[tm] = *(const bf16x8*)((const char*)A + SWZ(tm * 16 + l15, seg));
                afl[tm] = *(const bf16x8*)((const char*)A + SWZ(32 + tm * 16 + l15, seg));
            }
#pragma unroll
            for (int tn = 0; tn < 2; ++tn) {
                bfh[tn] = *(const bf16x8*)((const char*)Bb + SWZ(wave * 32 + tn * 16 + l15, seg));
                bfl[tn] = *(const bf16x8*)((const char*)Bb + SWZ(128 + wave * 32 + tn * 16 + l15, seg));
            }
#pragma unroll
            for (int tm = 0; tm < 2; ++tm)
#pragma unroll
                for (int tn = 0; tn < 2; ++tn) {
                    acc[tm][tn] = __builtin_amdgcn_mfma_f32_16x16x32_bf16(afh[tm], bfh[tn], acc[tm][tn], 0, 0, 0);
                    acc[tm][tn] = __builtin_amdgcn_mfma_f32_16x16x32_bf16(afh[tm], bfl[tn], acc[tm][tn], 0, 0, 0);
                    acc[tm][tn] = __builtin_amdgcn_mfma_f32_16x16x32_bf16(afl[tm], bfh[tn], acc[tm][tn], 0, 0, 0);
                }
        }
        // epilogue: C/D col=lane&15 (sample), row=quad*4+reg (query); depth-2 ladder
#pragma unroll
        for (int tn = 0; tn < 2; ++tn) {
            const float nm = nrmb[wave * 32 + tn * 16 + l15];
#pragma unroll
            for (int tm = 0; tm < 2; ++tm)
#pragma unroll
                for (int reg = 0; reg < 4; ++reg) {
                    float keyf = fmaf(-2.f, acc[tm][tn][reg], nm);
                    const int li = tm * 4 + reg;
                    float k0 = lad0[li];
                    lad0[li] = fminf(k0, keyf);
                    lad1[li] = fminf(fmaxf(keyf, k0), lad1[li]);   // clamp = med3
                }
        }
    }
    // dump partials: part[q][wave*16+l15] as float2 (128 floats / query)
#pragma unroll
    for (int tm = 0; tm < 2; ++tm)
#pragma unroll
        for (int reg = 0; reg < 4; ++reg) {
            const int r = tm * 16 + quad * 4 + reg;
            const int li = tm * 4 + reg;
            float2 v = {lad0[li], lad1[li]};
            *(float2*)(part + ((size_t)(q0g + r)) * 128 + (wave * 16 + l15) * 2) = v;
        }
}

// K2b: merge 128 partials/query -> tau. Thread per query; block 64 so all 256
// CUs participate. grid = NQ/64 = 256.
__global__ void __launch_bounds__(64) tau_m(const float* __restrict__ part,
                                            float* __restrict__ tau) {
    const int q = blockIdx.x * 64 + (int)threadIdx.x;
    const float4* p = reinterpret_cast<const float4*>(part + (size_t)q * 128);
    float key[K_];
#pragma unroll
    for (int j = 0; j < K_; ++j) key[j] = __builtin_inff();
    for (int i = 0; i < 32; ++i) {
        float4 v = p[i];
        topk_insertf<K_>(key, v.x); topk_insertf<K_>(key, v.y);
        topk_insertf<K_>(key, v.z); topk_insertf<K_>(key, v.w);
    }
    tau[q] = key[15] + SLOP;
}

// K3: MFMA filter, B-reuse, async staging. Block = 128q x 1024m (8 chunks of 128m).
// All A/B staging via global_load_lds width=16 (zero VGPRs, no spill). The XOR
// bank-swizzle is preserved by permuting the SOURCE seg (dest (r,s_d) loads global
// seg s_d^(r&7)); same 64-B lines -> coalescing intact; ds_read side unchanged.
// Per half: load afh/afl/bfh/bfl once, 3 split-term MFMAs from regs. Accepts ->
// LDS per-query lists (DS atomics), flushed to fixed per-(q,ms) slots.
// grid = 2*64*8 = 1024 blocks of 256 (2 blocks/CU at 77 KB LDS).
__global__ void __launch_bounds__(256, 2) filter_k(const unsigned short* __restrict__ xh,
                                                   const unsigned short* __restrict__ xl,
                                                   const float* __restrict__ nrm,
                                                   const float* __restrict__ tau,
                                                   unsigned short* __restrict__ cnt_pb,
                                                   unsigned short* __restrict__ buf2) {
    __shared__ alignas(16) unsigned short A[256 * 64];    // 32 KB: rows 0-127 hi, 128-255 lo
    __shared__ alignas(16) unsigned short Bb[256 * 64];   // 32 KB
    __shared__ alignas(16) float taub[128];
    __shared__ alignas(16) float nrmS[1024];              // 4 KB superblock norms
    __shared__ unsigned short lists[128 * CAPB];          // 8 KB
    __shared__ unsigned int cntL[128];
    const int tid = (int)threadIdx.x;
    const int bid = (int)blockIdx.x;
    const int b  = bid >> 9;
    const int qt = (bid >> 3) & 63;
    const int ms = bid & 7;
    const int q0 = qt * 128;
    const unsigned short* __restrict__ xhb = xh + (size_t)b * N_ * D_;
    const unsigned short* __restrict__ xlb = xl + (size_t)b * N_ * D_;
    const float* __restrict__ nb = nrm + b * N_;
    const int w = tid >> 6;                               // wave index (uniform per wave)

    // async stage A (hi+lo): dest linear u = k*256+tid -> (r=u>>3, s_d=u&7),
    // source seg s_g = s_d ^ (r&7). LDS base per (k, wave) is wave-uniform.
#pragma unroll
    for (int k = 0; k < 8; ++k) {
        int u = k * 256 + tid, r = u >> 3, sg = (u & 7) ^ (r & 7);
        const unsigned short* src = (r < 128) ? xhb + (size_t)(q0 + r) * D_
                                              : xlb + (size_t)(q0 + r - 128) * D_;
        gl_lds16((const char*)src + (sg << 4), (char*)A + (k << 12) + (w << 10));
    }
    {                                                     // async stage B chunk 0
        const int m0 = ms * 1024;
#pragma unroll
        for (int k = 0; k < 8; ++k) {
            int u = k * 256 + tid, r = u >> 3, sg = (u & 7) ^ (r & 7);
            const unsigned short* src = (r < 128) ? xhb + (size_t)(m0 + r) * D_
                                                  : xlb + (size_t)(m0 + r - 128) * D_;
            gl_lds16((const char*)src + (sg << 4), (char*)Bb + (k << 12) + (w << 10));
        }
    }
    *(float4*)(nrmS + tid * 4) = *(const float4*)(nb + ms * 1024 + tid * 4);
    if (tid < 128) { cntL[tid] = 0; taub[tid] = tau[(b << 13) + q0 + tid]; }
    __syncthreads();                                      // vmcnt drained by compiler

    const int lane = tid & 63;
    const int wq = w >> 1, wm = w & 1;                    // 64x64 wave subtile
    const int l15 = lane & 15, quad = lane >> 4;

    for (int mc = 0; mc < 8; ++mc) {
        f32x4 acc[4][4] = {};
#pragma unroll
        for (int half = 0; half < 2; ++half) {
            const int seg = half * 4 + quad;
            bf16x8 afh[4], afl[4], bfh[4], bfl[4];
#pragma unroll
            for (int tm = 0; tm < 4; ++tm) {
                afh[tm] = *(const bf16x8*)((const char*)A + SWZ(wq * 64 + tm * 16 + l15, seg));
                afl[tm] = *(const bf16x8*)((const char*)A + SWZ(128 + wq * 64 + tm * 16 + l15, seg));
            }
#pragma unroll
            for (int tn = 0; tn < 4; ++tn) {
                bfh[tn] = *(const bf16x8*)((const char*)Bb + SWZ(wm * 64 + tn * 16 + l15, seg));
                bfl[tn] = *(const bf16x8*)((const char*)Bb + SWZ(128 + wm * 64 + tn * 16 + l15, seg));
            }
#pragma unroll
            for (int tm = 0; tm < 4; ++tm)
#pragma unroll
                for (int tn = 0; tn < 4; ++tn) {
                    acc[tm][tn] = __builtin_amdgcn_mfma_f32_16x16x32_bf16(afh[tm], bfh[tn], acc[tm][tn], 0, 0, 0);
                    acc[tm][tn] = __builtin_amdgcn_mfma_f32_16x16x32_bf16(afh[tm], bfl[tn], acc[tm][tn], 0, 0, 0);
                    acc[tm][tn] = __builtin_amdgcn_mfma_f32_16x16x32_bf16(afl[tm], bfh[tn], acc[tm][tn], 0, 0, 0);
                }
        }

        // epilogue: C/D layout col=lane&15 (m), row=quad*4+reg (q)
        float nmv[4]; int mlv[4];
#pragma unroll
        for (int tn = 0; tn < 4; ++tn) {
            mlv[tn] = mc * 128 + wm * 64 + tn * 16 + l15;  // local m within superblock
            nmv[tn] = nrmS[mlv[tn]];
        }
        f32x4 t4v[4];
#pragma unroll
        for (int tm = 0; tm < 4; ++tm) {
            f32x4 t4 = *(const f32x4*)(taub + wq * 64 + tm * 16 + quad * 4);
            t4v[tm] = t4 + SLOP;
        }
#pragma unroll
        for (int tm = 0; tm < 4; ++tm)
#pragma unroll
            for (int tn = 0; tn < 4; ++tn)
#pragma unroll
                for (int reg = 0; reg < 4; ++reg) {
                    float keyf = fmaf(-2.f, acc[tm][tn][reg], nmv[tn]);
                    if (keyf <= t4v[tm][reg]) {
                        int ql = wq * 64 + tm * 16 + quad * 4 + reg;     // local q
                        unsigned pos = atomicAdd(&cntL[ql], 1u);         // LDS atomic
                        if (pos < CAPB) lists[ql * CAPB + pos] = (unsigned short)(ms * 1024 + mlv[tn]);
                    }
                }

        __syncthreads();                                   // all waves done reading Bb
        if (mc < 7) {                                      // async stage next B chunk
            const int m0n = ms * 1024 + (mc + 1) * 128;
#pragma unroll
            for (int k = 0; k < 8; ++k) {
                int u = k * 256 + tid, r = u >> 3, sg = (u & 7) ^ (r & 7);
                const unsigned short* src = (r < 128) ? xhb + (size_t)(m0n + r) * D_
                                                      : xlb + (size_t)(m0n + r - 128) * D_;
                gl_lds16((const char*)src + (sg << 4), (char*)Bb + (k << 12) + (w << 10));
            }
        }
        __syncthreads();                                   // Bb(mc+1) visible (vmcnt drain)
    }
    if (tid < 128) {                                       // flush to fixed slots
        int q = (b << 13) + q0 + tid;
        unsigned cn = cntL[tid]; cn = cn < CAPB ? cn : CAPB;
        cnt_pb[(size_t)q * MS + ms] = (unsigned short)cn;
        unsigned short* dst = buf2 + ((size_t)q * MS + ms) * CAPB;
        for (unsigned i = 0; i < cn; ++i) dst[i] = lists[tid * CAPB + i];
    }
}

// K4: exact f64 rerank, wave-per-query. Each lane computes one candidate's full
// 64-dim f64 distance (gather loads + LDS-broadcast Q); selection via 64-lane
// bitonic sort of packed u64 (dist,id) keys: keep top-16 in lanes 0-15, refill
// 48, resort. block 256 = 4 waves = 4 queries; grid = NQ/4 = 4096.
__global__ void __launch_bounds__(256) rerank_k(const float* __restrict__ x,
                                                const unsigned short* __restrict__ cnt_pb,
                                                const unsigned short* __restrict__ buf2,
                                                int* __restrict__ out) {
    __shared__ float Qs[4 * 64];                           // 1 KB query rows
    __shared__ unsigned short ids[4 * MS * CAPB];          // 2 KB compacted survivors
    const int tid = (int)threadIdx.x;
    const int w = tid >> 6, lane = tid & 63;
    const int q = blockIdx.x * 4 + w;
    const int b = q >> 13, n = q & (N_ - 1);
    const float* __restrict__ xb = x + (size_t)b * N_ * D_;
    Qs[w * 64 + lane] = xb[(size_t)n * D_ + lane];

    int off[MS + 1]; off[0] = 0;                           // all lanes compute same
#pragma unroll
    for (int ms = 0; ms < MS; ++ms) {
        int c = (int)cnt_pb[(size_t)q * MS + ms]; c = c < CAPB ? c : CAPB;
        off[ms + 1] = off[ms] + c;
    }
    const int total = off[MS];                             // >= 16 guaranteed (true top-16 pass)
    for (int idx = lane; idx < total; idx += 64) {         // compact ids into LDS
        int ms = 0;
#pragma unroll
        for (int t = 1; t < MS; ++t) ms += (idx >= off[t]) ? 1 : 0;
        ids[(w * MS) * CAPB + idx] = buf2[((size_t)q * MS + ms) * CAPB + (idx - off[ms])];
    }
    __syncthreads();

    unsigned long long v = ~0ull;
    int consumed = 0;
    bool first = true;
    while (first || consumed < total) {
        const int myIdx = first ? lane : consumed + lane - 16;
        const bool take = (first || lane >= 16) && myIdx < total;
        unsigned long long nk = ~0ull;
        if (take) {
            const int id = (int)ids[(w * MS) * CAPB + myIdx];
            const float* __restrict__ crow = xb + (size_t)id * D_;
            double a0 = 0.0, a1 = 0.0, a2 = 0.0, a3 = 0.0;
#pragma unroll
            for (int j = 0; j < 16; ++j) {
                const float4 c  = *(const float4*)(crow + j * 4);        // per-lane gather
                const float4 qv = *(const float4*)(Qs + w * 64 + j * 4); // uniform -> broadcast
                double d0 = (double)qv.x - (double)c.x; a0 = fma(d0, d0, a0);
                double d1 = (double)qv.y - (double)c.y; a1 = fma(d1, d1, a1);
                double d2 = (double)qv.z - (double)c.z; a2 = fma(d2, d2, a2);
                double d3 = (double)qv.w - (double)c.w; a3 = fma(d3, d3, a3);
            }
            double s = (a0 + a1) + (a2 + a3);
            // s >= 0 -> f64 bits order-preserving; low 13 mantissa bits carry the id
            // for exact (dist, id) lexicographic compare (ties -> lower id).
            nk = ((unsigned long long)__double_as_longlong(s) & ~0x1FFFull) | (unsigned)id;
        }
        if (first || lane >= 16) v = nk;                   // lanes 0-15 keep running top-16
        // 64-lane bitonic sort ascending (21 steps)
#pragma unroll
        for (int k = 2; k <= 64; k <<= 1)
#pragma unroll
            for (int j = k >> 1; j > 0; j >>= 1) {
                unsigned long long o = __shfl_xor(v, j, 64);
                const bool keepmin = (((lane & k) == 0) == ((lane & j) == 0));
                unsigned long long mn = v < o ? v : o;
                unsigned long long mx = v < o ? o : v;
                v = keepmin ? mn : mx;
            }
        consumed += first ? 64 : 48;
        first = false;
    }
    if (lane < K_) {
        out[(size_t)q * K_ + lane]                   = (int)(v & 0x1FFFull);  // nn_idx
        out[(size_t)NQ * K_ + (size_t)q * K_ + lane] = n;                     // center_idx
    }
}

extern "C" void kernel_launch(void* const* d_in, const int* in_sizes, int n_in,
                              void* d_out, int out_size, void* d_ws, size_t ws_size,
                              hipStream_t stream) {
    const float* x = (const float*)d_in[0];
    int* out = (int*)d_out;
    char* ws = (char*)d_ws;
    float*          nrm    = (float*)ws;                          //  64 KB @ 0
    float*          tau    = (float*)(ws + (64 << 10));           //  64 KB
    unsigned short* cnt_pb = (unsigned short*)(ws + (128 << 10)); // 256 KB (16384*8*2)
    unsigned short* xh     = (unsigned short*)(ws + (1 << 20));   //   2 MB
    unsigned short* xl     = (unsigned short*)(ws + (3 << 20));   //   2 MB
    unsigned short* buf2   = (unsigned short*)(ws + (5 << 20));   // 8.4 MB (16384*8*32*2)
    float*          part   = (float*)(ws + (5 << 20));            //   8 MB, ALIASES buf2:
    // part is written by tau_p and fully consumed by tau_m BEFORE filter_k writes buf2.

    hipLaunchKernelGGL(split_k,  dim3(1024), dim3(256), 0, stream, x, xh, xl, nrm);
    hipLaunchKernelGGL(tau_p,    dim3(512),  dim3(256), 0, stream, xh, xl, nrm, part);
    hipLaunchKernelGGL(tau_m,    dim3(256),  dim3(64),  0, stream, part, tau);
    hipLaunchKernelGGL(filter_k, dim3(1024), dim3(256), 0, stream, xh, xl, nrm, tau, cnt_pb, buf2);
    hipLaunchKernelGGL(rerank_k, dim3(4096), dim3(256), 0, stream, x, cnt_pb, buf2, out);
}